// Round 7
// baseline (759.942 us; speedup 1.0000x reference)
//
#include <hip/hip_runtime.h>
#include <math.h>

// EM routing (DigitCaps) B=16, N=16384, C=10, D=16, ITER_ROUTING=3.
// One votes pass per iteration accumulating sum(r), sum(r*v), sum(r*v^2)
// per (b,c,d) via wave-folded atomicAdd into tiny acc buffers; finalize
// kernels between passes. sigma via moment identity. Final act_out
// (beta_v/beta_a) never feeds returned miu -> skipped.
//
// R3: arrays by pointer -> scratch spill. R4: f32x16 also demoted.
// R5: 5.2 MB ws overflow stomped inputs. R6 (passed, 435us): latency-bound —
//     grid 1024 blocks = 50% max occupancy (measured 29%), VALUBusy 12%,
//     per-row loads serialized behind the shuffle chain (vmcnt(0)/row).
// R7 fix: CHUNKS 128 (2048 blocks -> 100% occupancy headroom) + explicit
//     next-row prefetch into named regs so loads overlap the shuffle chain.
//
// Thread map (256/block, 4 waves): lane = tid&63; rg = lane&31;
//   c = rg>>1 (c>=10 clamped+masked), half = rg&1 (owns d = 8h..8h+7),
//   row-slot = (lane>>5) + 2*wave -> 8 rows per block-step.

namespace {
constexpr int BB = 16, NN = 16384, CC = 10, DD = 16;
constexpr float EPSF = 1e-9f;
constexpr int CHUNKS = 128;                  // blocks per batch b
constexpr int ROWS = NN / CHUNKS;            // 128 rows per block
// acc buffer layout (floats)
constexpr int ACC_SZ = BB * CC * DD * 2 + BB * CC;  // rv | rv2 | rs = 5280
constexpr int RV_OFF = 0;
constexpr int RV2_OFF = BB * CC * DD;               // 2560
constexpr int RS_OFF = 2 * BB * CC * DD;            // 5120
constexpr int PAR_BASE = 3 * ACC_SZ;                // 15840 (x4B = 64B-aligned)
constexpr int PAR_SZ = 3 * BB * CC * DD + BB * CC;  // miu | A | i2s | act = 7840
constexpr int PMIU = 0;
constexpr int PA = BB * CC * DD;
constexpr int PI2S = 2 * BB * CC * DD;
constexpr int PACT = 3 * BB * CC * DD;
// total ws: 3*ACC_SZ + 2*PAR_SZ = 31520 floats = 126 KB (proven fit)
}  // namespace

__global__ void zero_acc(float* ws) {
  int i = blockIdx.x * blockDim.x + threadIdx.x;
  if (i < 3 * ACC_SZ) ws[i] = 0.0f;
}

// IT=0: r from activation only. IT=1: EM step, writes rv,rv2,rs.
// IT=2: EM step, rv,rs only.
template <int IT>
__global__ __launch_bounds__(256) void pass_k(const float* __restrict__ votes,
                                              const float* __restrict__ activ,
                                              const float* __restrict__ par,
                                              float* __restrict__ acc) {
  const int b = blockIdx.x / CHUNKS;
  const int chunk = blockIdx.x - b * CHUNKS;
  const int tid = threadIdx.x;
  const int wave = tid >> 6;
  const int lane = tid & 63;
  const int rg = lane & 31;
  const int c = rg >> 1;
  const int half = rg & 1;
  const int cc = c < CC ? c : CC - 1;
  const bool on = c < CC;
  const int rslot = (lane >> 5) + wave * 2;  // 0..7

  float4 mi0 = make_float4(0.f, 0.f, 0.f, 0.f), mi1 = mi0;
  float4 A0 = mi0, A1 = mi0, is0 = mi0, is1 = mi0;
  float actc = 0.f;
  if (IT != 0) {
    const float* pb = par + (b * CC + cc) * DD + half * 8;
    mi0 = *(const float4*)(pb + PMIU);
    mi1 = *(const float4*)(pb + PMIU + 4);
    A0 = *(const float4*)(pb + PA);
    A1 = *(const float4*)(pb + PA + 4);
    is0 = *(const float4*)(pb + PI2S);
    is1 = *(const float4*)(pb + PI2S + 4);
    actc = par[PACT + b * CC + cc];
  }

  float4 rv0 = make_float4(0.f, 0.f, 0.f, 0.f), rv1 = rv0;
  float4 rw0 = rv0, rw1 = rv0;
  float ar = 0.f;

  const int n0 = chunk * ROWS;
  const size_t rowoff = (size_t)cc * DD + half * 8;
  // software pipeline: prefetch row k's data before computing row k-8
  const float* vb = votes + (size_t)(b * NN + n0 + rslot) * (CC * DD) + rowoff;
  float4 p0 = *(const float4*)vb;
  float4 p1 = *(const float4*)(vb + 4);
  float pa = activ[b * NN + n0 + rslot];

  for (int k = rslot; k < ROWS; k += 8) {
    const float4 q0 = p0;
    const float4 q1 = p1;
    const float a = pa;
    // issue next row's loads (clamped on last iter -> reload same line)
    const int kn = (k + 8 < ROWS) ? k + 8 : k;
    const float* vn = votes + (size_t)(b * NN + n0 + kn) * (CC * DD) + rowoff;
    p0 = *(const float4*)vn;
    p1 = *(const float4*)(vn + 4);
    pa = activ[b * NN + n0 + kn];

    float r;
    if (IT == 0) {
      // r = (a/C)/(sum_c a/C + EPS) = (a/C)/(a+EPS); same for every c.
      r = (a * (1.0f / CC)) / (a + EPSF);
      ar += r;
    } else {
      float dx, s8 = 0.f;
      dx = q0.x - mi0.x; s8 += A0.x - dx * dx * is0.x;
      dx = q0.y - mi0.y; s8 += A0.y - dx * dx * is0.y;
      dx = q0.z - mi0.z; s8 += A0.z - dx * dx * is0.z;
      dx = q0.w - mi0.w; s8 += A0.w - dx * dx * is0.w;
      dx = q1.x - mi1.x; s8 += A1.x - dx * dx * is1.x;
      dx = q1.y - mi1.y; s8 += A1.y - dx * dx * is1.y;
      dx = q1.z - mi1.z; s8 += A1.z - dx * dx * is1.z;
      dx = q1.w - mi1.w; s8 += A1.w - dx * dx * is1.w;
      // S_c = sum_d log_p (pair merge); shift by max_c S (exact under ap/sum).
      const float S = s8 + __shfl_xor(s8, 1);
      float M = on ? S : -1e30f;
      M = fmaxf(M, __shfl_xor(M, 2));
      M = fmaxf(M, __shfl_xor(M, 4));
      M = fmaxf(M, __shfl_xor(M, 8));
      M = fmaxf(M, __shfl_xor(M, 16));
      const float te = on ? __expf(S - M) * actc : 0.f;
      float sap = te;  // sum over c: masks 2..16 never cross the half bit
      sap += __shfl_xor(sap, 2);
      sap += __shfl_xor(sap, 4);
      sap += __shfl_xor(sap, 8);
      sap += __shfl_xor(sap, 16);
      const float inv = 1.0f / (sap + EPSF);
      const float sr = a * sap * inv;  // = sum_c (ap/(sap+eps)*a)
      r = (te * inv * a) / (sr + EPSF);
      ar += r;
    }
    const float t0x = r * q0.x, t0y = r * q0.y, t0z = r * q0.z, t0w = r * q0.w;
    const float t1x = r * q1.x, t1y = r * q1.y, t1z = r * q1.z, t1w = r * q1.w;
    rv0.x += t0x; rv0.y += t0y; rv0.z += t0z; rv0.w += t0w;
    rv1.x += t1x; rv1.y += t1y; rv1.z += t1z; rv1.w += t1w;
    if (IT <= 1) {
      rw0.x += t0x * q0.x; rw0.y += t0y * q0.y; rw0.z += t0z * q0.z; rw0.w += t0w * q0.w;
      rw1.x += t1x * q1.x; rw1.y += t1y * q1.y; rw1.z += t1z * q1.z; rw1.w += t1w * q1.w;
    }
  }

  // fold the two row-slots of this wave (lane <-> lane+32)
  rv0.x += __shfl_down(rv0.x, 32); rv0.y += __shfl_down(rv0.y, 32);
  rv0.z += __shfl_down(rv0.z, 32); rv0.w += __shfl_down(rv0.w, 32);
  rv1.x += __shfl_down(rv1.x, 32); rv1.y += __shfl_down(rv1.y, 32);
  rv1.z += __shfl_down(rv1.z, 32); rv1.w += __shfl_down(rv1.w, 32);
  if (IT <= 1) {
    rw0.x += __shfl_down(rw0.x, 32); rw0.y += __shfl_down(rw0.y, 32);
    rw0.z += __shfl_down(rw0.z, 32); rw0.w += __shfl_down(rw0.w, 32);
    rw1.x += __shfl_down(rw1.x, 32); rw1.y += __shfl_down(rw1.y, 32);
    rw1.z += __shfl_down(rw1.z, 32); rw1.w += __shfl_down(rw1.w, 32);
  }
  ar += __shfl_down(ar, 32);

  if (lane < 32 && on) {
    float* rv = acc + RV_OFF + (b * CC + cc) * DD + half * 8;
    atomicAdd(&rv[0], rv0.x); atomicAdd(&rv[1], rv0.y);
    atomicAdd(&rv[2], rv0.z); atomicAdd(&rv[3], rv0.w);
    atomicAdd(&rv[4], rv1.x); atomicAdd(&rv[5], rv1.y);
    atomicAdd(&rv[6], rv1.z); atomicAdd(&rv[7], rv1.w);
    if (IT <= 1) {
      float* rw = acc + RV2_OFF + (b * CC + cc) * DD + half * 8;
      atomicAdd(&rw[0], rw0.x); atomicAdd(&rw[1], rw0.y);
      atomicAdd(&rw[2], rw0.z); atomicAdd(&rw[3], rw0.w);
      atomicAdd(&rw[4], rw1.x); atomicAdd(&rw[5], rw1.y);
      atomicAdd(&rw[6], rw1.z); atomicAdd(&rw[7], rw1.w);
    }
    if (half == 0) atomicAdd(&acc[RS_OFF + b * CC + cc], ar);
  }
}

// MODE=0: par_out = {miu, -0.5*ln(sig), 0.5/sig, act=softmax_c(rs)}.
// MODE=1: out = miu.
template <int MODE>
__global__ void finalize_k(const float* __restrict__ acc, float* __restrict__ par_out,
                           float* __restrict__ out) {
  const int idx = blockIdx.x * blockDim.x + threadIdx.x;
  if (idx < BB * CC * DD) {
    const int bc = idx / DD;
    const float rs = acc[RS_OFF + bc];
    const float den = rs + EPSF;
    const float miu = acc[RV_OFF + idx] / den;
    if (MODE == 1) {
      out[idx] = miu;
    } else {
      const float rv2 = acc[RV2_OFF + idx];
      const float Sf = rs / den;
      const float sig = rv2 / den - miu * miu * (2.0f - Sf) + EPSF;
      par_out[PMIU + idx] = miu;
      par_out[PA + idx] = -0.5f * logf(sig);
      par_out[PI2S + idx] = 0.5f / sig;
    }
  }
  if (MODE == 0 && blockIdx.x == 0 && threadIdx.x < BB) {
    const int b = threadIdx.x;
    float m = -1e30f;
    for (int i = 0; i < CC; ++i) m = fmaxf(m, acc[RS_OFF + b * CC + i]);
    float ss = 0.f;
    for (int i = 0; i < CC; ++i) ss += __expf(acc[RS_OFF + b * CC + i] - m);
    for (int i = 0; i < CC; ++i)
      par_out[PACT + b * CC + i] = __expf(acc[RS_OFF + b * CC + i] - m) / ss;
  }
}

extern "C" void kernel_launch(void* const* d_in, const int* in_sizes, int n_in,
                              void* d_out, int out_size, void* d_ws, size_t ws_size,
                              hipStream_t stream) {
  const float* votes = (const float*)d_in[0];
  const float* activ = (const float*)d_in[1];
  // d_in[2]/d_in[3] (beta_v, beta_a) only affect the post-final act_out,
  // which never feeds the returned miu -> unused.
  float* ws = (float*)d_ws;
  float* out = (float*)d_out;

  float* acc0 = ws;
  float* acc1 = ws + ACC_SZ;
  float* acc2 = ws + 2 * ACC_SZ;
  float* par0 = ws + PAR_BASE;
  float* par1 = ws + PAR_BASE + PAR_SZ;

  zero_acc<<<dim3((3 * ACC_SZ + 255) / 256), dim3(256), 0, stream>>>(ws);

  const dim3 gp(BB * CHUNKS), bp(256);
  const dim3 gf((BB * CC * DD + 255) / 256), bf(256);
  pass_k<0><<<gp, bp, 0, stream>>>(votes, activ, nullptr, acc0);
  finalize_k<0><<<gf, bf, 0, stream>>>(acc0, par0, nullptr);
  pass_k<1><<<gp, bp, 0, stream>>>(votes, activ, par0, acc1);
  finalize_k<0><<<gf, bf, 0, stream>>>(acc1, par1, nullptr);
  pass_k<2><<<gp, bp, 0, stream>>>(votes, activ, par1, acc2);
  finalize_k<1><<<gf, bf, 0, stream>>>(acc2, nullptr, out);
}